// Round 2
// baseline (5315.586 us; speedup 1.0000x reference)
//
#include <hip/hip_runtime.h>
#include <math.h>

// ---------- types / helpers ----------
typedef __attribute__((ext_vector_type(8))) short bf16x8;   // 8 bf16 = 4 VGPR
typedef __attribute__((ext_vector_type(4))) float f32x4;    // MFMA acc
typedef __attribute__((ext_vector_type(4))) unsigned short u16x4;

__device__ __forceinline__ unsigned short f2bf(float x) {   // round-to-nearest-even
  unsigned int u = __builtin_bit_cast(unsigned int, x);
  return (unsigned short)((u + 0x7fffu + ((u >> 16) & 1u)) >> 16);
}
__device__ __forceinline__ float bf2f(unsigned short h) {
  unsigned int u = ((unsigned int)h) << 16;
  return __builtin_bit_cast(float, u);
}
// tanh via hw exp2: tanh(z) = 1 - 2/(e^{2z}+1), e^{2z} = 2^{z*2*log2(e)}
__device__ __forceinline__ float fast_tanh(float z) {
  float e;
  asm("v_exp_f32 %0, %1" : "=v"(e) : "v"(z * 2.8853900817779268f));
  return 1.0f - 2.0f * __builtin_amdgcn_rcpf(e + 1.0f);
}

// ---------- K0: convert weights + h0 to bf16; zero barrier flags ----------
__global__ void convert_kernel(const float* __restrict__ w_i2h,
                               const float* __restrict__ w_h2o,
                               const float* __restrict__ h0,
                               unsigned short* __restrict__ wx,
                               unsigned short* __restrict__ wh,
                               unsigned short* __restrict__ w2o,
                               unsigned short* __restrict__ h_all,
                               int* __restrict__ flags) {
  int idx = blockIdx.x * 256 + threadIdx.x;
  if (idx < 256) flags[idx] = 0;           // barrier flags for rnn_scan
  int e = idx * 4;
  const float* src;
  unsigned short* dst;
  if (e < 2097152) {                       // w_i2h
    int row = e >> 11, col = e & 2047;
    src = w_i2h + e;
    dst = (col < 1024) ? (wx + row * 1024 + col) : (wh + row * 1024 + (col - 1024));
  } else if (e < 3145728) {                // w_h2o
    int i = e - 2097152; src = w_h2o + i; dst = w2o + i;
  } else {                                 // h0 -> h_all slice 0
    int i = e - 3145728; src = h0 + i; dst = h_all + i;
  }
  float4 v = *(const float4*)src;
  u16x4 o = {f2bf(v.x), f2bf(v.y), f2bf(v.z), f2bf(v.w)};
  *(u16x4*)dst = o;
}

// ---------- GEMM: C[M,N] = A[M,K] * B[N,K]^T + bias[N] ----------
// 128x128 tile, BK=64, 4 waves (2x2 of 64x64), 16x16x32 bf16 MFMA.
template <bool AF32, bool OUTBF16>
__global__ __launch_bounds__(256) void gemm_bt(const void* __restrict__ Ap,
                                               const unsigned short* __restrict__ B,
                                               const float* __restrict__ bias,
                                               void* __restrict__ Cp,
                                               int M, int N, int K) {
  __shared__ __attribute__((aligned(16))) unsigned short lA[128 * 64];
  __shared__ __attribute__((aligned(16))) unsigned short lB[128 * 64];
  const int tid = threadIdx.x;
  const int bx = blockIdx.x & 7;       // N/128 == 8
  const int by = blockIdx.x >> 3;
  const int lane = tid & 63, w = tid >> 6;
  const int g = lane >> 4, l15 = lane & 15;
  const int wm = w >> 1, wn = w & 1;

  f32x4 acc[4][4];
#pragma unroll
  for (int i = 0; i < 4; ++i)
#pragma unroll
    for (int j = 0; j < 4; ++j) acc[i][j] = (f32x4){0.f, 0.f, 0.f, 0.f};

  const int nK = K >> 6;
  for (int kt = 0; kt < nK; ++kt) {
    const int k0 = kt << 6;
#pragma unroll
    for (int i = 0; i < 4; ++i) {
      int cl = i * 256 + tid;
      int row = cl >> 3, cc = cl & 7;
      bf16x8 av;
      if (AF32) {
        const float* ap = (const float*)Ap + (size_t)(by * 128 + row) * K + k0 + cc * 8;
        float4 f0 = *(const float4*)ap;
        float4 f1 = *(const float4*)(ap + 4);
        av = (bf16x8){(short)f2bf(f0.x), (short)f2bf(f0.y), (short)f2bf(f0.z), (short)f2bf(f0.w),
                      (short)f2bf(f1.x), (short)f2bf(f1.y), (short)f2bf(f1.z), (short)f2bf(f1.w)};
      } else {
        const unsigned short* ap = (const unsigned short*)Ap + (size_t)(by * 128 + row) * K + k0 + cc * 8;
        av = *(const bf16x8*)ap;
      }
      *(bf16x8*)&lA[(row * 8 + (cc ^ (row & 7))) * 8] = av;
      const unsigned short* bp = B + (size_t)(bx * 128 + row) * K + k0 + cc * 8;
      bf16x8 bv = *(const bf16x8*)bp;
      *(bf16x8*)&lB[(row * 8 + (cc ^ (row & 7))) * 8] = bv;
    }
    __syncthreads();
#pragma unroll
    for (int kk = 0; kk < 2; ++kk) {
      bf16x8 av[4], bv[4];
#pragma unroll
      for (int mt = 0; mt < 4; ++mt) {
        int r = wm * 64 + mt * 16 + l15;
        av[mt] = *(const bf16x8*)&lA[(r * 8 + ((kk * 4 + g) ^ (r & 7))) * 8];
      }
#pragma unroll
      for (int nt = 0; nt < 4; ++nt) {
        int r = wn * 64 + nt * 16 + l15;
        bv[nt] = *(const bf16x8*)&lB[(r * 8 + ((kk * 4 + g) ^ (r & 7))) * 8];
      }
#pragma unroll
      for (int mt = 0; mt < 4; ++mt)
#pragma unroll
        for (int nt = 0; nt < 4; ++nt)
          acc[mt][nt] = __builtin_amdgcn_mfma_f32_16x16x32_bf16(av[mt], bv[nt], acc[mt][nt], 0, 0, 0);
    }
    __syncthreads();
  }
#pragma unroll
  for (int mt = 0; mt < 4; ++mt) {
    int grow = by * 128 + wm * 64 + mt * 16 + g * 4;
#pragma unroll
    for (int nt = 0; nt < 4; ++nt) {
      int col = bx * 128 + wn * 64 + nt * 16 + l15;
      float bs = bias[col];
#pragma unroll
      for (int r = 0; r < 4; ++r) {
        size_t off = (size_t)(grow + r) * N + col;
        float v = acc[mt][nt][r] + bs;
        if (OUTBF16) ((unsigned short*)Cp)[off] = f2bf(v);
        else ((float*)Cp)[off] = v;
      }
    }
  }
}

// ---------- K2: persistent recurrence scan ----------
// 256 blocks x 64 threads (1 wave). Block b: jt=b>>2 (16 j's), bt=b&3 (16 batches).
// wh slice [16][1024] bf16 stays in LDS all 512 steps (immune to L2 inv).
// Per-step sync: release-store flags[b]=t+1; poll all 256 flags >= t (relaxed
// agent atomic loads, no RMW contention), one acquire load on exit (cache inv).
#define SCAN_BLOCKS 256
__global__ __launch_bounds__(64, 1) void rnn_scan(const unsigned short* __restrict__ xproj,
                                                  const unsigned short* __restrict__ wh,
                                                  unsigned short* __restrict__ h_all,
                                                  int* __restrict__ flags) {
  __shared__ __attribute__((aligned(16))) unsigned short lW[16 * 1024];  // 32 KB, swizzled
  const int tid = threadIdx.x;          // 0..63
  const int b = blockIdx.x;
  const int jt = b >> 2, bt = b & 3;
  const int g = tid >> 4, l15 = tid & 15;
  const int j0 = jt * 16, b0 = bt * 16;

  // stage wh rows j0..j0+15 into LDS (chunk-XOR swizzle), once
  for (int i = tid; i < 16 * 128; i += 64) {
    int r = i >> 7, c = i & 127;
    bf16x8 v = *(const bf16x8*)(wh + (size_t)(j0 + r) * 1024 + c * 8);
    *(bf16x8*)&lW[(r * 128 + (c ^ (r & 7))) * 8] = v;
  }
  __syncthreads();

  for (int t = 0; t < 512; ++t) {
    const unsigned short* hsrc = h_all + (size_t)t * 65536;
    const unsigned short* xp   = xproj + (size_t)t * 65536;
    unsigned short* hdst       = h_all + (size_t)(t + 1) * 65536;

    // prefetch xp (independent of barrier): lane holds rows g*4+r, col l15
    float xpv[4];
#pragma unroll
    for (int r = 0; r < 4; ++r)
      xpv[r] = bf2f(xp[(size_t)(b0 + g * 4 + r) * 1024 + j0 + l15]);

    // wait for all blocks to have published step t
    {
      while (true) {
        int v0 = __hip_atomic_load(flags + tid,       __ATOMIC_RELAXED, __HIP_MEMORY_SCOPE_AGENT);
        int v1 = __hip_atomic_load(flags + 64 + tid,  __ATOMIC_RELAXED, __HIP_MEMORY_SCOPE_AGENT);
        int v2 = __hip_atomic_load(flags + 128 + tid, __ATOMIC_RELAXED, __HIP_MEMORY_SCOPE_AGENT);
        int v3 = __hip_atomic_load(flags + 192 + tid, __ATOMIC_RELAXED, __HIP_MEMORY_SCOPE_AGENT);
        if (__all(v0 >= t && v1 >= t && v2 >= t && v3 >= t)) break;
        __builtin_amdgcn_s_sleep(1);
      }
      // acquire: invalidate L1/L2 so h reads see remote writes
      __hip_atomic_load(flags, __ATOMIC_ACQUIRE, __HIP_MEMORY_SCOPE_AGENT);
    }

    // h[t] (16 batches x 1024) @ whT slice -> 16x16, K=1024: 32 MFMAs, 4 acc chains
    f32x4 acc[4];
#pragma unroll
    for (int i = 0; i < 4; ++i) acc[i] = (f32x4){0.f, 0.f, 0.f, 0.f};
#pragma unroll
    for (int kk = 0; kk < 32; ++kk) {
      bf16x8 a = *(const bf16x8*)(hsrc + (size_t)(b0 + l15) * 1024 + kk * 32 + g * 8);
      bf16x8 w = *(const bf16x8*)&lW[(l15 * 128 + ((kk * 4 + g) ^ (l15 & 7))) * 8];
      acc[kk & 3] = __builtin_amdgcn_mfma_f32_16x16x32_bf16(a, w, acc[kk & 3], 0, 0, 0);
    }
    f32x4 s = acc[0] + acc[1];
    s = s + acc[2];
    s = s + acc[3];

    // epilogue: batch = b0 + g*4 + r, j = j0 + l15
#pragma unroll
    for (int r = 0; r < 4; ++r) {
      float z = s[r] + xpv[r];
      hdst[(size_t)(b0 + g * 4 + r) * 1024 + j0 + l15] = f2bf(fast_tanh(z));
    }

    // publish step t+1 (release: h stores reach coherence point first)
    if (tid == 0)
      __hip_atomic_store(flags + b, t + 1, __ATOMIC_RELEASE, __HIP_MEMORY_SCOPE_AGENT);
  }
}

// ---------- launch ----------
extern "C" void kernel_launch(void* const* d_in, const int* in_sizes, int n_in,
                              void* d_out, int out_size, void* d_ws, size_t ws_size,
                              hipStream_t stream) {
  const float* x     = (const float*)d_in[0];   // (512,64,1024)
  const float* h0    = (const float*)d_in[1];   // (64,1024)
  const float* w_i2h = (const float*)d_in[2];   // (1024,2048)
  const float* b_i2h = (const float*)d_in[3];   // (1024)
  const float* w_h2o = (const float*)d_in[4];   // (1024,1024)
  const float* b_h2o = (const float*)d_in[5];   // (1024)

  // workspace: h_all (513*64*1024*2) | wx 2MB | wh 2MB | w2o 2MB
  char* ws = (char*)d_ws;
  unsigned short* h_all = (unsigned short*)ws;
  unsigned short* wx    = (unsigned short*)(ws + 67239936);
  unsigned short* wh    = wx + 1024 * 1024;
  unsigned short* w2o   = wh + 1024 * 1024;
  // d_out (128MB fp32 y): first 64MB doubles as bf16 xproj (dead before gemm2),
  // last 4KB holds the 256 barrier flags (overwritten by gemm2 at the end).
  unsigned short* xproj = (unsigned short*)d_out;
  int* flags = (int*)((char*)d_out + 134217728 - 4096);

  convert_kernel<<<3136, 256, 0, stream>>>(w_i2h, w_h2o, h0, wx, wh, w2o, h_all, flags);

  // xproj = x @ wx^T + b_i2h   (M=32768, N=1024, K=1024)
  gemm_bt<true, true><<<2048, 256, 0, stream>>>((const void*)x, wx, b_i2h,
                                                (void*)xproj, 32768, 1024, 1024);

  // persistent 512-step recurrence
  rnn_scan<<<SCAN_BLOCKS, 64, 0, stream>>>(xproj, wh, h_all, flags);

  // Y = h_all[1..512] @ w_h2o^T + b_h2o  -> d_out (fp32)
  gemm_bt<false, false><<<2048, 256, 0, stream>>>((const void*)(h_all + 65536), w2o, b_h2o,
                                                  d_out, 32768, 1024, 1024);
}

// Round 3
// 2144.475 us; speedup vs baseline: 2.4787x; 2.4787x over previous
//
#include <hip/hip_runtime.h>
#include <math.h>

// ---------- types / helpers ----------
typedef __attribute__((ext_vector_type(8))) short bf16x8;   // 8 bf16 = 4 VGPR
typedef __attribute__((ext_vector_type(4))) int   i32x4;
typedef __attribute__((ext_vector_type(4))) float f32x4;    // MFMA acc
typedef __attribute__((ext_vector_type(4))) unsigned short u16x4;

__device__ __forceinline__ unsigned short f2bf(float x) {   // round-to-nearest-even
  unsigned int u = __builtin_bit_cast(unsigned int, x);
  return (unsigned short)((u + 0x7fffu + ((u >> 16) & 1u)) >> 16);
}
__device__ __forceinline__ float bf2f(unsigned short h) {
  unsigned int u = ((unsigned int)h) << 16;
  return __builtin_bit_cast(float, u);
}
// tanh via hw exp2: tanh(z) = 1 - 2/(e^{2z}+1)
__device__ __forceinline__ float fast_tanh(float z) {
  float e;
  asm("v_exp_f32 %0, %1" : "=v"(e) : "v"(z * 2.8853900817779268f));
  return 1.0f - 2.0f * __builtin_amdgcn_rcpf(e + 1.0f);
}

// ---------- K0: convert weights + h0 to bf16; zero barrier flags ----------
__global__ void convert_kernel(const float* __restrict__ w_i2h,
                               const float* __restrict__ w_h2o,
                               const float* __restrict__ h0,
                               unsigned short* __restrict__ wx,
                               unsigned short* __restrict__ wh,
                               unsigned short* __restrict__ w2o,
                               unsigned short* __restrict__ h_all,
                               int* __restrict__ flags) {
  int idx = blockIdx.x * 256 + threadIdx.x;
  if (idx < 256) flags[idx] = 0;           // barrier flags for rnn_scan
  int e = idx * 4;
  const float* src;
  unsigned short* dst;
  if (e < 2097152) {                       // w_i2h
    int row = e >> 11, col = e & 2047;
    src = w_i2h + e;
    dst = (col < 1024) ? (wx + row * 1024 + col) : (wh + row * 1024 + (col - 1024));
  } else if (e < 3145728) {                // w_h2o
    int i = e - 2097152; src = w_h2o + i; dst = w2o + i;
  } else {                                 // h0 -> h_all slice 0
    int i = e - 3145728; src = h0 + i; dst = h_all + i;
  }
  float4 v = *(const float4*)src;
  u16x4 o = {f2bf(v.x), f2bf(v.y), f2bf(v.z), f2bf(v.w)};
  *(u16x4*)dst = o;
}

// ---------- GEMM: C[M,N] = A[M,K] * B[N,K]^T + bias[N] ----------
// 128x128 tile, BK=64, 4 waves (2x2 of 64x64), 16x16x32 bf16 MFMA.
template <bool AF32, bool OUTBF16>
__global__ __launch_bounds__(256) void gemm_bt(const void* __restrict__ Ap,
                                               const unsigned short* __restrict__ B,
                                               const float* __restrict__ bias,
                                               void* __restrict__ Cp,
                                               int M, int N, int K) {
  __shared__ __attribute__((aligned(16))) unsigned short lA[128 * 64];
  __shared__ __attribute__((aligned(16))) unsigned short lB[128 * 64];
  const int tid = threadIdx.x;
  const int bx = blockIdx.x & 7;       // N/128 == 8
  const int by = blockIdx.x >> 3;
  const int lane = tid & 63, w = tid >> 6;
  const int g = lane >> 4, l15 = lane & 15;
  const int wm = w >> 1, wn = w & 1;

  f32x4 acc[4][4];
#pragma unroll
  for (int i = 0; i < 4; ++i)
#pragma unroll
    for (int j = 0; j < 4; ++j) acc[i][j] = (f32x4){0.f, 0.f, 0.f, 0.f};

  const int nK = K >> 6;
  for (int kt = 0; kt < nK; ++kt) {
    const int k0 = kt << 6;
#pragma unroll
    for (int i = 0; i < 4; ++i) {
      int cl = i * 256 + tid;
      int row = cl >> 3, cc = cl & 7;
      bf16x8 av;
      if (AF32) {
        const float* ap = (const float*)Ap + (size_t)(by * 128 + row) * K + k0 + cc * 8;
        float4 f0 = *(const float4*)ap;
        float4 f1 = *(const float4*)(ap + 4);
        av = (bf16x8){(short)f2bf(f0.x), (short)f2bf(f0.y), (short)f2bf(f0.z), (short)f2bf(f0.w),
                      (short)f2bf(f1.x), (short)f2bf(f1.y), (short)f2bf(f1.z), (short)f2bf(f1.w)};
      } else {
        const unsigned short* ap = (const unsigned short*)Ap + (size_t)(by * 128 + row) * K + k0 + cc * 8;
        av = *(const bf16x8*)ap;
      }
      *(bf16x8*)&lA[(row * 8 + (cc ^ (row & 7))) * 8] = av;
      const unsigned short* bp = B + (size_t)(bx * 128 + row) * K + k0 + cc * 8;
      bf16x8 bv = *(const bf16x8*)bp;
      *(bf16x8*)&lB[(row * 8 + (cc ^ (row & 7))) * 8] = bv;
    }
    __syncthreads();
#pragma unroll
    for (int kk = 0; kk < 2; ++kk) {
      bf16x8 av[4], bv[4];
#pragma unroll
      for (int mt = 0; mt < 4; ++mt) {
        int r = wm * 64 + mt * 16 + l15;
        av[mt] = *(const bf16x8*)&lA[(r * 8 + ((kk * 4 + g) ^ (r & 7))) * 8];
      }
#pragma unroll
      for (int nt = 0; nt < 4; ++nt) {
        int r = wn * 64 + nt * 16 + l15;
        bv[nt] = *(const bf16x8*)&lB[(r * 8 + ((kk * 4 + g) ^ (r & 7))) * 8];
      }
#pragma unroll
      for (int mt = 0; mt < 4; ++mt)
#pragma unroll
        for (int nt = 0; nt < 4; ++nt)
          acc[mt][nt] = __builtin_amdgcn_mfma_f32_16x16x32_bf16(av[mt], bv[nt], acc[mt][nt], 0, 0, 0);
    }
    __syncthreads();
  }
#pragma unroll
  for (int mt = 0; mt < 4; ++mt) {
    int grow = by * 128 + wm * 64 + mt * 16 + g * 4;
#pragma unroll
    for (int nt = 0; nt < 4; ++nt) {
      int col = bx * 128 + wn * 64 + nt * 16 + l15;
      float bs = bias[col];
#pragma unroll
      for (int r = 0; r < 4; ++r) {
        size_t off = (size_t)(grow + r) * N + col;
        float v = acc[mt][nt][r] + bs;
        if (OUTBF16) ((unsigned short*)Cp)[off] = f2bf(v);
        else ((float*)Cp)[off] = v;
      }
    }
  }
}

// ---------- K2: persistent recurrence scan, coherent-access sync ----------
// 256 blocks x 64 threads (1 wave). Block b: jt=b>>2 (16 j's), bt=b&3 (16 batches).
// NO cache-maintenance ops: h and flags use sc0 sc1 (L1/L2-bypass, L3-coherent)
// inline-asm accesses only. wh fragments hoisted to registers for all 512 steps.
// Barrier is per-bt-group: block (jt,bt) only needs the 64 blocks sharing bt.
#define SCAN_BLOCKS 256
__global__ __launch_bounds__(64, 1) void rnn_scan(const unsigned short* __restrict__ xproj,
                                                  const unsigned short* __restrict__ wh,
                                                  unsigned short* __restrict__ h_all,
                                                  int* __restrict__ flags) {
  const int tid = threadIdx.x;          // 0..63
  const int b = blockIdx.x;
  const int jt = b >> 2, bt = b & 3;
  const int g = tid >> 4, l15 = tid & 15;
  const int j0 = jt * 16, b0 = bt * 16;

  // hoist wh B-fragments (step-invariant): wb[kk] = wh[j0+l15][kk*32+g*8 ..+7]
  bf16x8 wb[32];
#pragma unroll
  for (int kk = 0; kk < 32; ++kk)
    wb[kk] = *(const bf16x8*)(wh + (size_t)(j0 + l15) * 1024 + kk * 32 + g * 8);

  const int* fl = flags + bt * 64 + tid;   // lane tid polls producer jt'=tid of my bt group
  int* myflag = flags + bt * 64 + jt;

  for (int t = 0; t < 512; ++t) {
    const unsigned short* hsrc = h_all + (size_t)t * 65536 + (size_t)b0 * 1024;
    const unsigned short* xp   = xproj + (size_t)t * 65536;
    unsigned short* hdst       = h_all + (size_t)(t + 1) * 65536;

    // prefetch xp (normal cached loads; xproj is read-only from a prior kernel)
    float xpv[4];
#pragma unroll
    for (int r = 0; r < 4; ++r)
      xpv[r] = bf2f(xp[(size_t)(b0 + g * 4 + r) * 1024 + j0 + l15]);

    // barrier: wait for all 64 producers of my bt group (one coherent load/lane)
    int v;
    do {
      asm volatile("global_load_dword %0, %1, off sc0 sc1\n\ts_waitcnt vmcnt(0)"
                   : "=v"(v) : "v"(fl) : "memory");
    } while (__any(v < t));

    // coherent h loads: bypass L1/L2, read L3 (the cross-XCD coherence point)
    i32x4 ha[32];
#pragma unroll
    for (int kk = 0; kk < 32; ++kk) {
      const unsigned short* p = hsrc + (size_t)l15 * 1024 + kk * 32 + g * 8;
      asm volatile("global_load_dwordx4 %0, %1, off sc0 sc1"
                   : "=v"(ha[kk]) : "v"(p) : "memory");
    }

    f32x4 acc[4];
#pragma unroll
    for (int i = 0; i < 4; ++i) acc[i] = (f32x4){0.f, 0.f, 0.f, 0.f};

    // pipelined consume: counted vmcnt + sched_barrier (rule 18)
#define MFMA_GROUP(base, n)                                                     \
    asm volatile("s_waitcnt vmcnt(" #n ")" ::: "memory");                       \
    __builtin_amdgcn_sched_barrier(0);                                          \
    _Pragma("unroll")                                                           \
    for (int kk = base; kk < base + 8; ++kk)                                    \
      acc[kk & 3] = __builtin_amdgcn_mfma_f32_16x16x32_bf16(                    \
          __builtin_bit_cast(bf16x8, ha[kk]), wb[kk], acc[kk & 3], 0, 0, 0);

    MFMA_GROUP(0, 24)
    MFMA_GROUP(8, 16)
    MFMA_GROUP(16, 8)
    MFMA_GROUP(24, 0)
#undef MFMA_GROUP

    f32x4 s = (acc[0] + acc[1]) + (acc[2] + acc[3]);

    // epilogue: h_next = tanh(s + xp), coherent 2B stores (write-through to L3)
#pragma unroll
    for (int r = 0; r < 4; ++r) {
      float z = s[r] + xpv[r];
      unsigned int hv = f2bf(fast_tanh(z));
      unsigned short* p = hdst + (size_t)(b0 + g * 4 + r) * 1024 + j0 + l15;
      asm volatile("global_store_short %0, %1, off sc0 sc1"
                   :: "v"(p), "v"(hv) : "memory");
    }
    // order h stores before flag publish
    asm volatile("s_waitcnt vmcnt(0)" ::: "memory");
    if (tid == 0) {
      int tv = t + 1;
      asm volatile("global_store_dword %0, %1, off sc0 sc1"
                   :: "v"(myflag), "v"(tv) : "memory");
    }
  }
}

// ---------- launch ----------
extern "C" void kernel_launch(void* const* d_in, const int* in_sizes, int n_in,
                              void* d_out, int out_size, void* d_ws, size_t ws_size,
                              hipStream_t stream) {
  const float* x     = (const float*)d_in[0];   // (512,64,1024)
  const float* h0    = (const float*)d_in[1];   // (64,1024)
  const float* w_i2h = (const float*)d_in[2];   // (1024,2048)
  const float* b_i2h = (const float*)d_in[3];   // (1024)
  const float* w_h2o = (const float*)d_in[4];   // (1024,1024)
  const float* b_h2o = (const float*)d_in[5];   // (1024)

  // workspace: h_all (513*64*1024*2) | wx 2MB | wh 2MB | w2o 2MB
  char* ws = (char*)d_ws;
  unsigned short* h_all = (unsigned short*)ws;
  unsigned short* wx    = (unsigned short*)(ws + 67239936);
  unsigned short* wh    = wx + 1024 * 1024;
  unsigned short* w2o   = wh + 1024 * 1024;
  // d_out (128MB fp32 y): first 64MB doubles as bf16 xproj (dead before gemm2),
  // last 4KB holds the 256 barrier flags (overwritten by gemm2 at the end).
  unsigned short* xproj = (unsigned short*)d_out;
  int* flags = (int*)((char*)d_out + 134217728 - 4096);

  convert_kernel<<<3136, 256, 0, stream>>>(w_i2h, w_h2o, h0, wx, wh, w2o, h_all, flags);

  // xproj = x @ wx^T + b_i2h   (M=32768, N=1024, K=1024)
  gemm_bt<true, true><<<2048, 256, 0, stream>>>((const void*)x, wx, b_i2h,
                                                (void*)xproj, 32768, 1024, 1024);

  // persistent 512-step recurrence (coherent-access sync, no cache maintenance)
  rnn_scan<<<SCAN_BLOCKS, 64, 0, stream>>>(xproj, wh, h_all, flags);

  // Y = h_all[1..512] @ w_h2o^T + b_h2o  -> d_out (fp32)
  gemm_bt<false, false><<<2048, 256, 0, stream>>>((const void*)(h_all + 65536), w2o, b_h2o,
                                                  d_out, 32768, 1024, 1024);
}